// Round 10
// baseline (1733.800 us; speedup 1.0000x reference)
//
#include <hip/hip_runtime.h>

#define N_NODES 20000
#define N_EDGES 320000
#define R_RUNS 10
#define HID 64
#define NG 128
#define NC 10
#define NL 4
#define MROWS (R_RUNS * N_NODES)   // 200000
#define BN_EPS 1e-5f
#define NCOPY 16                   // stats copies per buffer
#define TS 72                      // LDS z-tile row stride (bf16 elems)

typedef __bf16 bf16;
typedef __attribute__((ext_vector_type(8))) __bf16 bf16x8;
typedef __attribute__((ext_vector_type(4))) float f32x4;
typedef unsigned int uint32;

// ---------------- workspace layout (bytes)
constexpr size_t OFF_FLAGS   = 0;          // int[4] counters
constexpr size_t OFF_TICKETS = 64;         // int[8]: ag1 per layer, gemm2 per layer
constexpr size_t OFF_CURSOR  = 256;        // int[20001] -> pad 80384
constexpr size_t OFF_STATS   = 80640;      // f32[8 bufs][16 copies][128] = 65536
constexpr size_t OFF_POOLED5 = 146176;     // f32[5][128][64] = 163840
constexpr size_t ZERO_BYTES  = 310016;
constexpr size_t OFF_SCSH    = 310016;     // f32 sc1[64] sh1[64] sc2[64] sh2[64] = 1024
constexpr size_t OFF_ROWST   = 311040;     // int[20001] -> pad 391424
constexpr size_t OFF_COL     = 391424;     // int[320000] -> 1671424
constexpr size_t OFF_PARAMS  = 1671424;    // bf16[37554] -> pad 1746688
constexpr size_t OFF_XB      = 1746688;    // bf16[1280000] -> 4306688
constexpr size_t OFF_H       = 4306688;    // 25,600,000
constexpr size_t OFF_Z       = 29906688;   // 25,600,000 -> end 55,506,688

// params block element offsets (w1/w2 stored PRE-SWIZZLED in B-fragment order)
#define PW1  0
#define PB1  16384
#define PG1  16640
#define PBB1 16896
#define PW2  17152
#define PB2  33536
#define PG2  33792
#define PBB2 34048
#define PFW  34304
#define PFB  37504
#define PTOT 37554
#define CVT_TOT (1280000 + PTOT)

// ---------------- runtime dtype detection (validated R4-R9) ----------------
__global__ void detect_kernel(const unsigned short* __restrict__ xu,
                              const unsigned int* __restrict__ mw,
                              int* __restrict__ cnts) {
    int tid = blockIdx.x * 256 + threadIdx.x;   // 16384 threads
    int insane = 0, lowp = 0, f32w = 0, gt1 = 0;
    for (int i = tid; i < 4096; i += 16384) {
        unsigned int u = xu[2 * i];
        if (((u >> 7) & 0xFFu) >= 0x90u) insane++;
    }
    for (int i = tid; i < 50000; i += 16384) {
        unsigned int w = mw[i];
        if ((w & 0xFFFFu) == 0x3F80u) lowp = 1;
        else if (w == 0x3F800000u) f32w = 1;
        else if (w > 1u) gt1 = 1;
    }
    if (insane) atomicAdd(&cnts[0], insane);
    if (lowp)   atomicOr(&cnts[1], 1);
    if (f32w)   atomicOr(&cnts[2], 1);
    if (gt1)    atomicOr(&cnts[3], 1);
}

__device__ inline bf16 ld_any(const void* p, int i, int f32mode) {
    if (f32mode) return (bf16)((const float*)p)[i];
    return ((const bf16*)p)[i];
}

// convert all float inputs to canonical bf16; w1/w2 written in per-lane
// B-fragment order:
//   Wf[((nt*2+c)*64 + lane)*8 + j] = W[(c*32+(lane>>4)*8+j)*64 + nt*16+(lane&15)]
__global__ void convert_kernel(const int* __restrict__ cnts,
                               const void* x, const void* w1, const void* b1,
                               const void* g1, const void* bb1, const void* w2,
                               const void* b2, const void* g2, const void* bb2,
                               const void* fw, const void* fb,
                               bf16* __restrict__ xb, bf16* __restrict__ params) {
    int t = blockIdx.x * 256 + threadIdx.x;
    if (t >= CVT_TOT) return;
    int f = cnts[0] > 64;
    if (t < 1280000) { xb[t] = ld_any(x, t, f); return; }
    int u = t - 1280000;
    if (u < PB1 || (u >= PW2 && u < PB2)) {       // swizzled weight regions
        const void* src = (u < PB1) ? w1 : w2;
        int v = (u < PB1) ? u : u - PW2;
        int layer = v >> 12, rem = v & 4095;
        int j = rem & 7, lane = (rem >> 3) & 63, ntc = rem >> 9;
        int nt = ntc >> 1, c = ntc & 1;
        int k = c * 32 + (lane >> 4) * 8 + j;
        int n = nt * 16 + (lane & 15);
        params[u] = ld_any(src, layer * 4096 + k * 64 + n, f);
        return;
    }
    const void* src; int base;
    if      (u < PG1)  { src = b1;  base = PB1; }
    else if (u < PBB1) { src = g1;  base = PG1; }
    else if (u < PW2)  { src = bb1; base = PBB1; }
    else if (u < PG2)  { src = b2;  base = PB2; }
    else if (u < PBB2) { src = g2;  base = PG2; }
    else if (u < PFW)  { src = bb2; base = PBB2; }
    else if (u < PFB)  { src = fw;  base = PFW; }
    else               { src = fb;  base = PFB; }
    params[u] = ld_any(src, u - base, f);
}

// h0[(n*10+r)*64+f] = drop[r][n] ? 0 : x[n,f]  (contiguous writes, R7-proven)
__global__ void build_h0_kernel(const bf16* __restrict__ xb, const void* __restrict__ maskp,
                                const int* __restrict__ cnts, bf16* __restrict__ h) {
    int i = blockIdx.x * 256 + threadIdx.x;   // (n*10+r)*8 + c ; 1.6M total
    int c = i & 7;
    int rowid = i >> 3;
    int r = rowid % R_RUNS;
    int n = rowid / R_RUNS;
    size_t midx = (size_t)r * N_NODES + n;
    int w = cnts[1] ? 2 : (cnts[2] ? 4 : (cnts[3] ? 1 : 4));
    int dropped;
    if (w == 1)      dropped = ((const unsigned char*)maskp)[midx] != 0;
    else if (w == 2) dropped = ((const unsigned short*)maskp)[midx] != 0;
    else             dropped = ((const unsigned int*)maskp)[midx] != 0;
    bf16x8 v;
    if (dropped) {
        #pragma unroll
        for (int j = 0; j < 8; ++j) v[j] = (bf16)0.0f;
    } else {
        v = *(const bf16x8*)(xb + (size_t)n * HID + c * 8);
    }
    *(bf16x8*)(h + (size_t)rowid * HID + c * 8) = v;
}

// level-0 raw pool of h0 (R7-proven)
__global__ __launch_bounds__(256) void pool0_kernel(const bf16* __restrict__ t,
                                                    const int* __restrict__ batch,
                                                    float* __restrict__ pooled) {
    int gid = blockIdx.x * 256 + threadIdx.x;   // n*64+f
    int f = gid & 63, n = gid >> 6;
    size_t base = (size_t)n * (R_RUNS * HID) + f;
    float s = 0.f;
    #pragma unroll
    for (int r = 0; r < R_RUNS; ++r) s += (float)t[base + r * HID];
    atomicAdd(&pooled[batch[n] * HID + f], s * (1.0f / R_RUNS));
}

// ---------------- CSR build (keyed by dst) ----------------
__global__ void csr_count_kernel(const int* __restrict__ ei, int* __restrict__ deg) {
    int e = blockIdx.x * 256 + threadIdx.x;
    if (e < N_EDGES) atomicAdd(&deg[ei[N_EDGES + e]], 1);
}

__global__ void csr_scan_kernel(int* __restrict__ deg, int* __restrict__ row_start) {
    __shared__ int lds[1024];
    int tid = threadIdx.x;
    const int CH = 20;
    int base = tid * CH;
    int local[CH];
    int s = 0;
    #pragma unroll
    for (int j = 0; j < CH; ++j) {
        int n = base + j;
        int d = (n < N_NODES) ? deg[n] : 0;
        local[j] = d; s += d;
    }
    lds[tid] = s; __syncthreads();
    for (int off = 1; off < 1024; off <<= 1) {
        int add = (tid >= off) ? lds[tid - off] : 0;
        __syncthreads();
        lds[tid] += add;
        __syncthreads();
    }
    int excl = lds[tid] - s;
    #pragma unroll
    for (int j = 0; j < CH; ++j) {
        int n = base + j;
        if (n < N_NODES) { row_start[n] = excl; deg[n] = excl; excl += local[j]; }
    }
    if (tid == 1023) row_start[N_NODES] = lds[1023];
}

__global__ void csr_fill_kernel(const int* __restrict__ ei, int* __restrict__ cursor,
                                int* __restrict__ col) {
    int e = blockIdx.x * 256 + threadIdx.x;
    if (e < N_EDGES) {
        int src = ei[e];
        int dst = ei[N_EDGES + e];
        int pos = atomicAdd(&cursor[dst], 1);
        col[pos] = src;
    }
}

// shared helper: last-block ticket -> reduce NCOPY stats -> scale/shift
__device__ inline void finalize_stats(int tid, const float* statsP,
                                      const bf16* gamma, const bf16* beta,
                                      float* scaleOut, float* shiftOut,
                                      float* lstat) {
    if (tid < 128) {
        float s = 0.f;
        #pragma unroll
        for (int k = 0; k < NCOPY; ++k)
            s += __hip_atomic_load(&statsP[k * 128 + tid], __ATOMIC_RELAXED,
                                   __HIP_MEMORY_SCOPE_AGENT);
        lstat[tid] = s;
    }
    __syncthreads();
    if (tid < 64) {
        float mu = lstat[tid] * (1.0f / MROWS);
        float var = lstat[tid + 64] * (1.0f / MROWS) - mu * mu;
        float rs = rsqrtf(var + BN_EPS);
        float a = (float)gamma[tid] * rs;
        scaleOut[tid] = a;
        shiftOut[tid] = (float)beta[tid] - mu * a;
    }
}

// ---------------- fused agg + gemm1 (R9-proven win): block = 16 nodes.
// Phase 1: waves gather neighbor sums into LDS z-tile. Phase 2: MFMA gemm1
// from LDS -> t(global) + stats1. Last block (ticket) finalizes scale1/shift1.
__global__ __launch_bounds__(256) void ag1_kernel(const uint32* __restrict__ hD,
                                                  const int* __restrict__ row_start,
                                                  const int* __restrict__ col,
                                                  const bf16* __restrict__ Wf,
                                                  const bf16* __restrict__ bias,
                                                  bf16* __restrict__ out,
                                                  float* __restrict__ statsOut,
                                                  int* __restrict__ ticket,
                                                  const bf16* __restrict__ gamma,
                                                  const bf16* __restrict__ beta,
                                                  float* __restrict__ scaleOut,
                                                  float* __restrict__ shiftOut) {
    __shared__ __align__(16) bf16 zT[16 * R_RUNS * TS];   // 160 x 72 = 23040 B
    __shared__ float lsum[64], lsq[64], lstat[128];
    __shared__ int isLast;
    uint32* zTu = (uint32*)zT;                            // row stride 36 dwords
    int tid = threadIdx.x;
    int wave = tid >> 6, lane = tid & 63, l16 = lane & 15, quad = lane >> 4;
    int b = blockIdx.x;
    const int NODE_DW = R_RUNS * HID / 2;   // 320

    if (tid < 64) { lsum[tid] = 0.f; lsq[tid] = 0.f; }

    // ---- phase 1: aggregate 4 nodes per wave into LDS
    for (int i = 0; i < 4; ++i) {
        int nl = wave + 4 * i;              // local node 0..15
        int n = b * 16 + nl;
        size_t base4 = (size_t)n * NODE_DW + lane * 4;
        size_t baset = (size_t)n * NODE_DW + 256 + lane;
        float acc[10];
        {
            uint4 u = *(const uint4*)(hD + base4);
            uint32 tw = hD[baset];
            acc[0] = __uint_as_float(u.x << 16); acc[1] = __uint_as_float(u.x & 0xFFFF0000u);
            acc[2] = __uint_as_float(u.y << 16); acc[3] = __uint_as_float(u.y & 0xFFFF0000u);
            acc[4] = __uint_as_float(u.z << 16); acc[5] = __uint_as_float(u.z & 0xFFFF0000u);
            acc[6] = __uint_as_float(u.w << 16); acc[7] = __uint_as_float(u.w & 0xFFFF0000u);
            acc[8] = __uint_as_float(tw << 16);  acc[9] = __uint_as_float(tw & 0xFFFF0000u);
        }
        int beg = row_start[n], end = row_start[n + 1];
        int idx = beg;
        for (; idx + 4 <= end; idx += 4) {
            uint4 a[4]; uint32 tw[4];
            #pragma unroll
            for (int u = 0; u < 4; ++u) {
                size_t o = (size_t)col[idx + u] * NODE_DW;
                a[u] = *(const uint4*)(hD + o + lane * 4);
                tw[u] = hD[o + 256 + lane];
            }
            #pragma unroll
            for (int u = 0; u < 4; ++u) {
                uint32 wd[4] = {a[u].x, a[u].y, a[u].z, a[u].w};
                #pragma unroll
                for (int c = 0; c < 4; ++c) {
                    acc[2 * c]     += __uint_as_float(wd[c] << 16);
                    acc[2 * c + 1] += __uint_as_float(wd[c] & 0xFFFF0000u);
                }
                acc[8] += __uint_as_float(tw[u] << 16);
                acc[9] += __uint_as_float(tw[u] & 0xFFFF0000u);
            }
        }
        for (; idx < end; ++idx) {
            size_t o = (size_t)col[idx] * NODE_DW;
            uint4 a0 = *(const uint4*)(hD + o + lane * 4);
            uint32 t0 = hD[o + 256 + lane];
            uint32 wd[4] = {a0.x, a0.y, a0.z, a0.w};
            #pragma unroll
            for (int c = 0; c < 4; ++c) {
                acc[2 * c]     += __uint_as_float(wd[c] << 16);
                acc[2 * c + 1] += __uint_as_float(wd[c] & 0xFFFF0000u);
            }
            acc[8] += __uint_as_float(t0 << 16);
            acc[9] += __uint_as_float(t0 & 0xFFFF0000u);
        }
        #pragma unroll
        for (int c = 0; c < 5; ++c) {
            int d = (c < 4) ? (lane * 4 + c) : (256 + lane);
            int rL = nl * R_RUNS + (d >> 5);
            int fp = d & 31;
            unsigned short lo = __builtin_bit_cast(unsigned short, (bf16)acc[2 * c]);
            unsigned short hi = __builtin_bit_cast(unsigned short, (bf16)acc[2 * c + 1]);
            zTu[rL * (TS / 2) + fp] = (uint32)lo | ((uint32)hi << 16);
        }
    }
    __syncthreads();

    // ---- phase 2: gemm1 from LDS
    bf16x8 bfr[4][2];
    #pragma unroll
    for (int nt = 0; nt < 4; ++nt)
        #pragma unroll
        for (int c = 0; c < 2; ++c)
            bfr[nt][c] = *(const bf16x8*)(Wf + (size_t)((nt * 2 + c) * 64 + lane) * 8);
    float bvs[4];
    #pragma unroll
    for (int nt = 0; nt < 4; ++nt) bvs[nt] = (float)bias[nt * 16 + l16];

    for (int g = wave; g < 10; g += 4) {
        const bf16* tp = &zT[(g * 16 + l16) * TS];
        bf16x8 a0 = *(const bf16x8*)(tp + quad * 8);
        bf16x8 a1 = *(const bf16x8*)(tp + 32 + quad * 8);
        f32x4 acc[4];
        #pragma unroll
        for (int nt = 0; nt < 4; ++nt) acc[nt] = (f32x4){bvs[nt], bvs[nt], bvs[nt], bvs[nt]};
        #pragma unroll
        for (int nt = 0; nt < 4; ++nt) {
            acc[nt] = __builtin_amdgcn_mfma_f32_16x16x32_bf16(a0, bfr[nt][0], acc[nt], 0, 0, 0);
            acc[nt] = __builtin_amdgcn_mfma_f32_16x16x32_bf16(a1, bfr[nt][1], acc[nt], 0, 0, 0);
        }
        size_t rowBase = (size_t)b * 160 + g * 16;
        #pragma unroll
        for (int nt = 0; nt < 4; ++nt) {
            float ss = 0.f, qq = 0.f;
            #pragma unroll
            for (int reg = 0; reg < 4; ++reg) {
                float v = acc[nt][reg];
                ss += v; qq += v * v;
                out[(rowBase + quad * 4 + reg) * HID + nt * 16 + l16] = (bf16)v;
            }
            atomicAdd(&lsum[nt * 16 + l16], ss);
            atomicAdd(&lsq[nt * 16 + l16], qq);
        }
    }
    __syncthreads();
    if (tid < 64) {
        int copy = b & (NCOPY - 1);
        atomicAdd(&statsOut[copy * 128 + tid], lsum[tid]);
        atomicAdd(&statsOut[copy * 128 + 64 + tid], lsq[tid]);
    }
    // ---- ticket: last block finalizes scale1/shift1
    if (tid == 0) {
        __threadfence();
        int old = __hip_atomic_fetch_add(ticket, 1, __ATOMIC_ACQ_REL,
                                         __HIP_MEMORY_SCOPE_AGENT);
        isLast = (old == (int)gridDim.x - 1);
    }
    __syncthreads();
    if (isLast)
        finalize_stats(tid, statsOut, gamma, beta, scaleOut, shiftOut, lstat);
}

// ---------------- gemm2: out = bn_relu(in) @ W + bias, + stats2.
// Reads precomputed scale1/shift1 (512B). Last block finalizes scale2/shift2.
// in/out may alias (per-wave 16-row slice).
__global__ __launch_bounds__(256) void gemm64_kernel(const bf16* in,
                                                     const bf16* __restrict__ Wf,
                                                     const bf16* __restrict__ bias,
                                                     bf16* out,
                                                     const float* __restrict__ scaleIn,
                                                     const float* __restrict__ shiftIn,
                                                     float* __restrict__ statsOut,
                                                     int* __restrict__ ticket,
                                                     const bf16* __restrict__ gamma,
                                                     const bf16* __restrict__ beta,
                                                     float* __restrict__ scaleOut,
                                                     float* __restrict__ shiftOut) {
    __shared__ float lscale[64], lshift[64];
    __shared__ float lsum[64], lsq[64], lstat[128];
    __shared__ int isLast;
    int tid = threadIdx.x;
    int wave = tid >> 6, lane = tid & 63, l16 = lane & 15, quad = lane >> 4;

    if (tid < 64) {
        lscale[tid] = scaleIn[tid];
        lshift[tid] = shiftIn[tid];
        lsum[tid] = 0.f; lsq[tid] = 0.f;
    }
    __syncthreads();

    size_t rowBase = (size_t)blockIdx.x * 64 + wave * 16;

    bf16x8 bfrag[4][2];
    #pragma unroll
    for (int nt = 0; nt < 4; ++nt)
        #pragma unroll
        for (int c = 0; c < 2; ++c)
            bfrag[nt][c] = *(const bf16x8*)(Wf + (size_t)((nt * 2 + c) * 64 + lane) * 8);

    f32x4 acc[4];
    #pragma unroll
    for (int nt = 0; nt < 4; ++nt) {
        float bv = (float)bias[nt * 16 + l16];
        acc[nt] = (f32x4){bv, bv, bv, bv};
    }

    size_t row = rowBase + l16;
    bf16x8 afrag[2];
    #pragma unroll
    for (int c = 0; c < 2; ++c) {
        int k0 = c * 32 + quad * 8;
        bf16x8 v = *(const bf16x8*)(in + row * HID + k0);
        #pragma unroll
        for (int j = 0; j < 8; ++j) {
            float f = (float)v[j] * lscale[k0 + j] + lshift[k0 + j];
            v[j] = (bf16)fmaxf(f, 0.f);
        }
        afrag[c] = v;
    }

    #pragma unroll
    for (int nt = 0; nt < 4; ++nt) {
        acc[nt] = __builtin_amdgcn_mfma_f32_16x16x32_bf16(afrag[0], bfrag[nt][0], acc[nt], 0, 0, 0);
        acc[nt] = __builtin_amdgcn_mfma_f32_16x16x32_bf16(afrag[1], bfrag[nt][1], acc[nt], 0, 0, 0);
    }

    #pragma unroll
    for (int nt = 0; nt < 4; ++nt)
        #pragma unroll
        for (int reg = 0; reg < 4; ++reg) {
            size_t orow = rowBase + quad * 4 + reg;
            out[orow * HID + nt * 16 + l16] = (bf16)acc[nt][reg];
        }

    #pragma unroll
    for (int nt = 0; nt < 4; ++nt) {
        float s = 0.f, q = 0.f;
        #pragma unroll
        for (int reg = 0; reg < 4; ++reg) { float v = acc[nt][reg]; s += v; q += v * v; }
        atomicAdd(&lsum[nt * 16 + l16], s);
        atomicAdd(&lsq[nt * 16 + l16], q);
    }
    __syncthreads();
    if (tid < 64) {
        int copy = blockIdx.x & (NCOPY - 1);
        atomicAdd(&statsOut[copy * 128 + tid], lsum[tid]);
        atomicAdd(&statsOut[copy * 128 + 64 + tid], lsq[tid]);
    }
    if (tid == 0) {
        __threadfence();
        int old = __hip_atomic_fetch_add(ticket, 1, __ATOMIC_ACQ_REL,
                                         __HIP_MEMORY_SCOPE_AGENT);
        isLast = (old == (int)gridDim.x - 1);
    }
    __syncthreads();
    if (isLast)
        finalize_stats(tid, statsOut, gamma, beta, scaleOut, shiftOut, lstat);
}

// BN2+ReLU + h-materialize + pool; reads precomputed scale2/shift2 (no LDS).
__global__ __launch_bounds__(256) void pool_bn_kernel(const bf16* __restrict__ t,
                                                      const float* __restrict__ scaleIn,
                                                      const float* __restrict__ shiftIn,
                                                      bf16* __restrict__ hOut,
                                                      const int* __restrict__ batch,
                                                      float* __restrict__ pooled) {
    int tid = threadIdx.x;
    int gid = blockIdx.x * 256 + tid;   // n*64+f
    int f = tid & 63, n = gid >> 6;
    float sc = scaleIn[f], sh = shiftIn[f];
    size_t base = (size_t)n * (R_RUNS * HID) + f;
    float s = 0.f;
    #pragma unroll
    for (int r = 0; r < R_RUNS; ++r) {
        float v = (float)t[base + r * HID];
        v = fmaxf(v * sc + sh, 0.f);
        hOut[base + r * HID] = (bf16)v;
        s += v;
    }
    atomicAdd(&pooled[batch[n] * HID + f], s * (1.0f / R_RUNS));
}

// final: out[g,:] = log_softmax( sum_l pooled5[l][g] @ fcw_l + fcb_l )
__global__ void fc_softmax_kernel(const float* __restrict__ pooled5,
                                  const bf16* __restrict__ params,
                                  const int* __restrict__ cnts, void* __restrict__ out) {
    int g = threadIdx.x;   // 128 threads
    if (g >= NG) return;
    float o[NC];
    #pragma unroll
    for (int c = 0; c < NC; ++c) o[c] = 0.f;
    for (int l = 0; l < NL + 1; ++l) {
        const float* pg = pooled5 + ((size_t)l * NG + g) * HID;
        const bf16* fw = params + PFW + l * (HID * NC);
        for (int k = 0; k < HID; ++k) {
            float p = pg[k];
            #pragma unroll
            for (int c = 0; c < NC; ++c) o[c] += p * (float)fw[k * NC + c];
        }
        #pragma unroll
        for (int c = 0; c < NC; ++c) o[c] += (float)params[PFB + l * NC + c];
    }
    float m = -1e30f;
    #pragma unroll
    for (int c = 0; c < NC; ++c) m = fmaxf(m, o[c]);
    float s = 0.f;
    #pragma unroll
    for (int c = 0; c < NC; ++c) s += expf(o[c] - m);
    float lg = logf(s);
    int f = cnts[0] > 64;
    #pragma unroll
    for (int c = 0; c < NC; ++c) {
        float val = o[c] - m - lg;
        if (f) ((float*)out)[g * NC + c] = val;
        else   ((bf16*)out)[g * NC + c] = (bf16)val;
    }
}

extern "C" void kernel_launch(void* const* d_in, const int* in_sizes, int n_in,
                              void* d_out, int out_size, void* d_ws, size_t ws_size,
                              hipStream_t stream) {
    const void* x     = d_in[0];
    const int*  ei    = (const int*)d_in[1];
    const int*  batch = (const int*)d_in[2];
    const void* maskp = d_in[3];

    char* ws = (char*)d_ws;
    int*   cnts    = (int*)(ws + OFF_FLAGS);
    int*   tickets = (int*)(ws + OFF_TICKETS);
    int*   cursor  = (int*)(ws + OFF_CURSOR);
    float* statsb  = (float*)(ws + OFF_STATS);
    float* pooled5 = (float*)(ws + OFF_POOLED5);
    float* scsh    = (float*)(ws + OFF_SCSH);   // sc1|sh1|sc2|sh2 (64 each)
    int*   rowst   = (int*)(ws + OFF_ROWST);
    int*   colbuf  = (int*)(ws + OFF_COL);
    bf16*  params  = (bf16*)(ws + OFF_PARAMS);
    bf16*  xb      = (bf16*)(ws + OFF_XB);
    bf16*  h       = (bf16*)(ws + OFF_H);
    bf16*  z       = (bf16*)(ws + OFF_Z);
    float* sc1 = scsh, *sh1 = scsh + 64, *sc2 = scsh + 128, *sh2 = scsh + 192;

    hipMemsetAsync(ws, 0, ZERO_BYTES, stream);   // flags+tickets+cursor+stats+pooled5

    detect_kernel<<<64, 256, 0, stream>>>((const unsigned short*)x,
                                          (const unsigned int*)maskp, cnts);
    convert_kernel<<<(CVT_TOT + 255) / 256, 256, 0, stream>>>(
        cnts, x, d_in[4], d_in[5], d_in[6], d_in[7], d_in[8], d_in[9], d_in[10],
        d_in[11], d_in[12], d_in[13], xb, params);

    csr_count_kernel<<<(N_EDGES + 255) / 256, 256, 0, stream>>>(ei, cursor);
    csr_scan_kernel<<<1, 1024, 0, stream>>>(cursor, rowst);
    csr_fill_kernel<<<(N_EDGES + 255) / 256, 256, 0, stream>>>(ei, cursor, colbuf);

    build_h0_kernel<<<(MROWS * 8) / 256, 256, 0, stream>>>(xb, maskp, cnts, h);
    pool0_kernel<<<(N_NODES * HID) / 256, 256, 0, stream>>>(h, batch, pooled5);

    for (int i = 0; i < NL; ++i) {
        float* st1 = statsb + (size_t)(2 * i) * (NCOPY * 128);
        float* st2 = statsb + (size_t)(2 * i + 1) * (NCOPY * 128);

        ag1_kernel<<<N_NODES / 16, 256, 0, stream>>>(
            (const uint32*)h, rowst, colbuf,
            params + PW1 + i * 4096, params + PB1 + i * 64, z, st1,
            &tickets[i], params + PG1 + i * 64, params + PBB1 + i * 64, sc1, sh1);

        gemm64_kernel<<<MROWS / 64, 256, 0, stream>>>(
            z, params + PW2 + i * 4096, params + PB2 + i * 64, z,
            sc1, sh1, st2,
            &tickets[4 + i], params + PG2 + i * 64, params + PBB2 + i * 64, sc2, sh2);

        pool_bn_kernel<<<(N_NODES * HID) / 256, 256, 0, stream>>>(
            z, sc2, sh2, h, batch, pooled5 + (size_t)(i + 1) * NG * HID);
    }

    fc_softmax_kernel<<<1, 128, 0, stream>>>(pooled5, params, cnts, d_out);
}

// Round 11
// 819.992 us; speedup vs baseline: 2.1144x; 2.1144x over previous
//
#include <hip/hip_runtime.h>

#define N_NODES 20000
#define N_EDGES 320000
#define R_RUNS 10
#define HID 64
#define NG 128
#define NC 10
#define NL 4
#define MROWS (R_RUNS * N_NODES)   // 200000
#define BN_EPS 1e-5f
#define NCOPY 16                   // stats copies per buffer
#define TS 72                      // LDS z-tile row stride (bf16 elems)

typedef __bf16 bf16;
typedef __attribute__((ext_vector_type(8))) __bf16 bf16x8;
typedef __attribute__((ext_vector_type(4))) float f32x4;
typedef unsigned int uint32;

// ---------------- workspace layout (bytes)
constexpr size_t OFF_FLAGS   = 0;          // int[4] counters, pad 256
constexpr size_t OFF_CURSOR  = 256;        // int[20001] -> pad 80384
constexpr size_t OFF_STATS   = 80640;      // f32[8 bufs][16 copies][128] = 65536
constexpr size_t OFF_POOLED5 = 146176;     // f32[5][128][64] = 163840
constexpr size_t ZERO_BYTES  = 310016;
constexpr size_t OFF_ROWST   = 310016;     // int[20001] -> pad 390400
constexpr size_t OFF_COL     = 390400;     // int[320000] -> 1670400
constexpr size_t OFF_PARAMS  = 1670400;    // bf16[37554] -> pad 1745664
constexpr size_t OFF_XB      = 1745664;    // bf16[1280000] -> 4305664
constexpr size_t OFF_H       = 4305664;    // 25,600,000
constexpr size_t OFF_Z       = 29905664;   // 25,600,000 -> end 55,505,664

// params block element offsets (w1/w2 stored PRE-SWIZZLED in B-fragment order)
#define PW1  0
#define PB1  16384
#define PG1  16640
#define PBB1 16896
#define PW2  17152
#define PB2  33536
#define PG2  33792
#define PBB2 34048
#define PFW  34304
#define PFB  37504
#define PTOT 37554
#define CVT_TOT (1280000 + PTOT)

// ---------------- runtime dtype detection (validated R4-R10) ----------------
__global__ void detect_kernel(const unsigned short* __restrict__ xu,
                              const unsigned int* __restrict__ mw,
                              int* __restrict__ cnts) {
    int tid = blockIdx.x * 256 + threadIdx.x;   // 16384 threads
    int insane = 0, lowp = 0, f32w = 0, gt1 = 0;
    for (int i = tid; i < 4096; i += 16384) {
        unsigned int u = xu[2 * i];
        if (((u >> 7) & 0xFFu) >= 0x90u) insane++;
    }
    for (int i = tid; i < 50000; i += 16384) {
        unsigned int w = mw[i];
        if ((w & 0xFFFFu) == 0x3F80u) lowp = 1;
        else if (w == 0x3F800000u) f32w = 1;
        else if (w > 1u) gt1 = 1;
    }
    if (insane) atomicAdd(&cnts[0], insane);
    if (lowp)   atomicOr(&cnts[1], 1);
    if (f32w)   atomicOr(&cnts[2], 1);
    if (gt1)    atomicOr(&cnts[3], 1);
}

__device__ inline bf16 ld_any(const void* p, int i, int f32mode) {
    if (f32mode) return (bf16)((const float*)p)[i];
    return ((const bf16*)p)[i];
}

// convert all float inputs to canonical bf16; w1/w2 written in per-lane
// B-fragment order:
//   Wf[((nt*2+c)*64 + lane)*8 + j] = W[(c*32+(lane>>4)*8+j)*64 + nt*16+(lane&15)]
__global__ void convert_kernel(const int* __restrict__ cnts,
                               const void* x, const void* w1, const void* b1,
                               const void* g1, const void* bb1, const void* w2,
                               const void* b2, const void* g2, const void* bb2,
                               const void* fw, const void* fb,
                               bf16* __restrict__ xb, bf16* __restrict__ params) {
    int t = blockIdx.x * 256 + threadIdx.x;
    if (t >= CVT_TOT) return;
    int f = cnts[0] > 64;
    if (t < 1280000) { xb[t] = ld_any(x, t, f); return; }
    int u = t - 1280000;
    if (u < PB1 || (u >= PW2 && u < PB2)) {       // swizzled weight regions
        const void* src = (u < PB1) ? w1 : w2;
        int v = (u < PB1) ? u : u - PW2;
        int layer = v >> 12, rem = v & 4095;
        int j = rem & 7, lane = (rem >> 3) & 63, ntc = rem >> 9;
        int nt = ntc >> 1, c = ntc & 1;
        int k = c * 32 + (lane >> 4) * 8 + j;
        int n = nt * 16 + (lane & 15);
        params[u] = ld_any(src, layer * 4096 + k * 64 + n, f);
        return;
    }
    const void* src; int base;
    if      (u < PG1)  { src = b1;  base = PB1; }
    else if (u < PBB1) { src = g1;  base = PG1; }
    else if (u < PW2)  { src = bb1; base = PBB1; }
    else if (u < PG2)  { src = b2;  base = PB2; }
    else if (u < PBB2) { src = g2;  base = PG2; }
    else if (u < PFW)  { src = bb2; base = PBB2; }
    else if (u < PFB)  { src = fw;  base = PFW; }
    else               { src = fb;  base = PFB; }
    params[u] = ld_any(src, u - base, f);
}

// h0[(n*10+r)*64+f] = drop[r][n] ? 0 : x[n,f]  (contiguous writes, R7-proven)
__global__ void build_h0_kernel(const bf16* __restrict__ xb, const void* __restrict__ maskp,
                                const int* __restrict__ cnts, bf16* __restrict__ h) {
    int i = blockIdx.x * 256 + threadIdx.x;   // (n*10+r)*8 + c ; 1.6M total
    int c = i & 7;
    int rowid = i >> 3;
    int r = rowid % R_RUNS;
    int n = rowid / R_RUNS;
    size_t midx = (size_t)r * N_NODES + n;
    int w = cnts[1] ? 2 : (cnts[2] ? 4 : (cnts[3] ? 1 : 4));
    int dropped;
    if (w == 1)      dropped = ((const unsigned char*)maskp)[midx] != 0;
    else if (w == 2) dropped = ((const unsigned short*)maskp)[midx] != 0;
    else             dropped = ((const unsigned int*)maskp)[midx] != 0;
    bf16x8 v;
    if (dropped) {
        #pragma unroll
        for (int j = 0; j < 8; ++j) v[j] = (bf16)0.0f;
    } else {
        v = *(const bf16x8*)(xb + (size_t)n * HID + c * 8);
    }
    *(bf16x8*)(h + (size_t)rowid * HID + c * 8) = v;
}

// level-0 raw pool of h0 (R7-proven)
__global__ __launch_bounds__(256) void pool0_kernel(const bf16* __restrict__ t,
                                                    const int* __restrict__ batch,
                                                    float* __restrict__ pooled) {
    int gid = blockIdx.x * 256 + threadIdx.x;   // n*64+f
    int f = gid & 63, n = gid >> 6;
    size_t base = (size_t)n * (R_RUNS * HID) + f;
    float s = 0.f;
    #pragma unroll
    for (int r = 0; r < R_RUNS; ++r) s += (float)t[base + r * HID];
    atomicAdd(&pooled[batch[n] * HID + f], s * (1.0f / R_RUNS));
}

// ---------------- CSR build (keyed by dst) ----------------
__global__ void csr_count_kernel(const int* __restrict__ ei, int* __restrict__ deg) {
    int e = blockIdx.x * 256 + threadIdx.x;
    if (e < N_EDGES) atomicAdd(&deg[ei[N_EDGES + e]], 1);
}

__global__ void csr_scan_kernel(int* __restrict__ deg, int* __restrict__ row_start) {
    __shared__ int lds[1024];
    int tid = threadIdx.x;
    const int CH = 20;
    int base = tid * CH;
    int local[CH];
    int s = 0;
    #pragma unroll
    for (int j = 0; j < CH; ++j) {
        int n = base + j;
        int d = (n < N_NODES) ? deg[n] : 0;
        local[j] = d; s += d;
    }
    lds[tid] = s; __syncthreads();
    for (int off = 1; off < 1024; off <<= 1) {
        int add = (tid >= off) ? lds[tid - off] : 0;
        __syncthreads();
        lds[tid] += add;
        __syncthreads();
    }
    int excl = lds[tid] - s;
    #pragma unroll
    for (int j = 0; j < CH; ++j) {
        int n = base + j;
        if (n < N_NODES) { row_start[n] = excl; deg[n] = excl; excl += local[j]; }
    }
    if (tid == 1023) row_start[N_NODES] = lds[1023];
}

__global__ void csr_fill_kernel(const int* __restrict__ ei, int* __restrict__ cursor,
                                int* __restrict__ col) {
    int e = blockIdx.x * 256 + threadIdx.x;
    if (e < N_EDGES) {
        int src = ei[e];
        int dst = ei[N_EDGES + e];
        int pos = atomicAdd(&cursor[dst], 1);
        col[pos] = src;
    }
}

// ---------------- fused agg + gemm1 (R9-proven): block = 16 nodes.
// Phase 1: waves gather neighbor sums into LDS z-tile. Phase 2: MFMA gemm1
// from LDS -> t(global) + stats1 atomics. NO ticket/fence (R10 lesson:
// per-block __threadfence = L2 flush storm, 5x kernel slowdown).
__global__ __launch_bounds__(256) void ag1_kernel(const uint32* __restrict__ hD,
                                                  const int* __restrict__ row_start,
                                                  const int* __restrict__ col,
                                                  const bf16* __restrict__ Wf,
                                                  const bf16* __restrict__ bias,
                                                  bf16* __restrict__ out,
                                                  float* __restrict__ statsOut) {
    __shared__ __align__(16) bf16 zT[16 * R_RUNS * TS];   // 160 x 72 = 23040 B
    __shared__ float lsum[64], lsq[64];
    uint32* zTu = (uint32*)zT;                            // row stride 36 dwords
    int tid = threadIdx.x;
    int wave = tid >> 6, lane = tid & 63, l16 = lane & 15, quad = lane >> 4;
    int b = blockIdx.x;
    const int NODE_DW = R_RUNS * HID / 2;   // 320

    if (tid < 64) { lsum[tid] = 0.f; lsq[tid] = 0.f; }

    // ---- phase 1: aggregate 4 nodes per wave into LDS
    for (int i = 0; i < 4; ++i) {
        int nl = wave + 4 * i;              // local node 0..15
        int n = b * 16 + nl;
        size_t base4 = (size_t)n * NODE_DW + lane * 4;
        size_t baset = (size_t)n * NODE_DW + 256 + lane;
        float acc[10];
        {
            uint4 u = *(const uint4*)(hD + base4);
            uint32 tw = hD[baset];
            acc[0] = __uint_as_float(u.x << 16); acc[1] = __uint_as_float(u.x & 0xFFFF0000u);
            acc[2] = __uint_as_float(u.y << 16); acc[3] = __uint_as_float(u.y & 0xFFFF0000u);
            acc[4] = __uint_as_float(u.z << 16); acc[5] = __uint_as_float(u.z & 0xFFFF0000u);
            acc[6] = __uint_as_float(u.w << 16); acc[7] = __uint_as_float(u.w & 0xFFFF0000u);
            acc[8] = __uint_as_float(tw << 16);  acc[9] = __uint_as_float(tw & 0xFFFF0000u);
        }
        int beg = row_start[n], end = row_start[n + 1];
        int idx = beg;
        for (; idx + 4 <= end; idx += 4) {
            uint4 a[4]; uint32 tw[4];
            #pragma unroll
            for (int u = 0; u < 4; ++u) {
                size_t o = (size_t)col[idx + u] * NODE_DW;
                a[u] = *(const uint4*)(hD + o + lane * 4);
                tw[u] = hD[o + 256 + lane];
            }
            #pragma unroll
            for (int u = 0; u < 4; ++u) {
                uint32 wd[4] = {a[u].x, a[u].y, a[u].z, a[u].w};
                #pragma unroll
                for (int c = 0; c < 4; ++c) {
                    acc[2 * c]     += __uint_as_float(wd[c] << 16);
                    acc[2 * c + 1] += __uint_as_float(wd[c] & 0xFFFF0000u);
                }
                acc[8] += __uint_as_float(tw[u] << 16);
                acc[9] += __uint_as_float(tw[u] & 0xFFFF0000u);
            }
        }
        for (; idx < end; ++idx) {
            size_t o = (size_t)col[idx] * NODE_DW;
            uint4 a0 = *(const uint4*)(hD + o + lane * 4);
            uint32 t0 = hD[o + 256 + lane];
            uint32 wd[4] = {a0.x, a0.y, a0.z, a0.w};
            #pragma unroll
            for (int c = 0; c < 4; ++c) {
                acc[2 * c]     += __uint_as_float(wd[c] << 16);
                acc[2 * c + 1] += __uint_as_float(wd[c] & 0xFFFF0000u);
            }
            acc[8] += __uint_as_float(t0 << 16);
            acc[9] += __uint_as_float(t0 & 0xFFFF0000u);
        }
        #pragma unroll
        for (int c = 0; c < 5; ++c) {
            int d = (c < 4) ? (lane * 4 + c) : (256 + lane);
            int rL = nl * R_RUNS + (d >> 5);
            int fp = d & 31;
            unsigned short lo = __builtin_bit_cast(unsigned short, (bf16)acc[2 * c]);
            unsigned short hi = __builtin_bit_cast(unsigned short, (bf16)acc[2 * c + 1]);
            zTu[rL * (TS / 2) + fp] = (uint32)lo | ((uint32)hi << 16);
        }
    }
    __syncthreads();

    // ---- phase 2: gemm1 from LDS, 10 row-groups of 16, waves strided
    bf16x8 bfr[4][2];
    #pragma unroll
    for (int nt = 0; nt < 4; ++nt)
        #pragma unroll
        for (int c = 0; c < 2; ++c)
            bfr[nt][c] = *(const bf16x8*)(Wf + (size_t)((nt * 2 + c) * 64 + lane) * 8);
    float bvs[4];
    #pragma unroll
    for (int nt = 0; nt < 4; ++nt) bvs[nt] = (float)bias[nt * 16 + l16];

    for (int g = wave; g < 10; g += 4) {
        const bf16* tp = &zT[(g * 16 + l16) * TS];
        bf16x8 a0 = *(const bf16x8*)(tp + quad * 8);
        bf16x8 a1 = *(const bf16x8*)(tp + 32 + quad * 8);
        f32x4 acc[4];
        #pragma unroll
        for (int nt = 0; nt < 4; ++nt) acc[nt] = (f32x4){bvs[nt], bvs[nt], bvs[nt], bvs[nt]};
        #pragma unroll
        for (int nt = 0; nt < 4; ++nt) {
            acc[nt] = __builtin_amdgcn_mfma_f32_16x16x32_bf16(a0, bfr[nt][0], acc[nt], 0, 0, 0);
            acc[nt] = __builtin_amdgcn_mfma_f32_16x16x32_bf16(a1, bfr[nt][1], acc[nt], 0, 0, 0);
        }
        size_t rowBase = (size_t)b * 160 + g * 16;
        #pragma unroll
        for (int nt = 0; nt < 4; ++nt) {
            float ss = 0.f, qq = 0.f;
            #pragma unroll
            for (int reg = 0; reg < 4; ++reg) {
                float v = acc[nt][reg];
                ss += v; qq += v * v;
                out[(rowBase + quad * 4 + reg) * HID + nt * 16 + l16] = (bf16)v;
            }
            atomicAdd(&lsum[nt * 16 + l16], ss);
            atomicAdd(&lsq[nt * 16 + l16], qq);
        }
    }
    __syncthreads();
    if (tid < 64) {
        int copy = b & (NCOPY - 1);
        atomicAdd(&statsOut[copy * 128 + tid], lsum[tid]);
        atomicAdd(&statsOut[copy * 128 + 64 + tid], lsq[tid]);
    }
}

// ---------------- gemm2 (R7-proven): out = bn_relu(in) @ W + bias, + stats.
// Consumer-side reduce of 16-copy raw stats (hot L2, <1us aggregate).
// in/out may alias (per-wave 16-row slice).
__global__ __launch_bounds__(256) void gemm64_kernel(const bf16* in,
                                                     const bf16* __restrict__ Wf,
                                                     const bf16* __restrict__ bias,
                                                     bf16* out,
                                                     const float* __restrict__ statsIn,
                                                     const bf16* __restrict__ gammaIn,
                                                     const bf16* __restrict__ betaIn,
                                                     float* __restrict__ statsOut) {
    __shared__ float lstat[128];
    __shared__ float lscale[64], lshift[64];
    __shared__ float lsum[64], lsq[64];
    int tid = threadIdx.x;
    int wave = tid >> 6, lane = tid & 63, l16 = lane & 15, quad = lane >> 4;

    if (tid < 128) {
        float s = 0.f;
        #pragma unroll
        for (int k = 0; k < NCOPY; ++k) s += statsIn[k * 128 + tid];
        lstat[tid] = s;
    }
    if (tid < 64) { lsum[tid] = 0.f; lsq[tid] = 0.f; }
    __syncthreads();
    if (tid < 64) {
        float mu = lstat[tid] * (1.0f / MROWS);
        float var = lstat[tid + 64] * (1.0f / MROWS) - mu * mu;
        float rs = rsqrtf(var + BN_EPS);
        float a = (float)gammaIn[tid] * rs;
        lscale[tid] = a;
        lshift[tid] = (float)betaIn[tid] - mu * a;
    }
    __syncthreads();

    size_t rowBase = (size_t)blockIdx.x * 64 + wave * 16;

    bf16x8 bfrag[4][2];
    #pragma unroll
    for (int nt = 0; nt < 4; ++nt)
        #pragma unroll
        for (int c = 0; c < 2; ++c)
            bfrag[nt][c] = *(const bf16x8*)(Wf + (size_t)((nt * 2 + c) * 64 + lane) * 8);

    f32x4 acc[4];
    #pragma unroll
    for (int nt = 0; nt < 4; ++nt) {
        float bv = (float)bias[nt * 16 + l16];
        acc[nt] = (f32x4){bv, bv, bv, bv};
    }

    size_t row = rowBase + l16;
    bf16x8 afrag[2];
    #pragma unroll
    for (int c = 0; c < 2; ++c) {
        int k0 = c * 32 + quad * 8;
        bf16x8 v = *(const bf16x8*)(in + row * HID + k0);
        #pragma unroll
        for (int j = 0; j < 8; ++j) {
            float f = (float)v[j] * lscale[k0 + j] + lshift[k0 + j];
            v[j] = (bf16)fmaxf(f, 0.f);
        }
        afrag[c] = v;
    }

    #pragma unroll
    for (int nt = 0; nt < 4; ++nt) {
        acc[nt] = __builtin_amdgcn_mfma_f32_16x16x32_bf16(afrag[0], bfrag[nt][0], acc[nt], 0, 0, 0);
        acc[nt] = __builtin_amdgcn_mfma_f32_16x16x32_bf16(afrag[1], bfrag[nt][1], acc[nt], 0, 0, 0);
    }

    #pragma unroll
    for (int nt = 0; nt < 4; ++nt)
        #pragma unroll
        for (int reg = 0; reg < 4; ++reg) {
            size_t orow = rowBase + quad * 4 + reg;
            out[orow * HID + nt * 16 + l16] = (bf16)acc[nt][reg];
        }

    #pragma unroll
    for (int nt = 0; nt < 4; ++nt) {
        float s = 0.f, q = 0.f;
        #pragma unroll
        for (int reg = 0; reg < 4; ++reg) { float v = acc[nt][reg]; s += v; q += v * v; }
        atomicAdd(&lsum[nt * 16 + l16], s);
        atomicAdd(&lsq[nt * 16 + l16], q);
    }
    __syncthreads();
    if (tid < 64) {
        int copy = blockIdx.x & (NCOPY - 1);
        atomicAdd(&statsOut[copy * 128 + tid], lsum[tid]);
        atomicAdd(&statsOut[copy * 128 + 64 + tid], lsq[tid]);
    }
}

// fused stats reduce + BN+ReLU + h-materialize + pool (R7-proven).
__global__ __launch_bounds__(256) void pool_bn_kernel(const bf16* __restrict__ t,
                                                      const float* __restrict__ statsIn,
                                                      const bf16* __restrict__ gammaIn,
                                                      const bf16* __restrict__ betaIn,
                                                      bf16* __restrict__ hOut,
                                                      const int* __restrict__ batch,
                                                      float* __restrict__ pooled) {
    __shared__ float lstat[128], lscale[64], lshift[64];
    int tid = threadIdx.x;
    if (tid < 128) {
        float s = 0.f;
        #pragma unroll
        for (int k = 0; k < NCOPY; ++k) s += statsIn[k * 128 + tid];
        lstat[tid] = s;
    }
    __syncthreads();
    if (tid < 64) {
        float mu = lstat[tid] * (1.0f / MROWS);
        float var = lstat[tid + 64] * (1.0f / MROWS) - mu * mu;
        float rs = rsqrtf(var + BN_EPS);
        float a = (float)gammaIn[tid] * rs;
        lscale[tid] = a;
        lshift[tid] = (float)betaIn[tid] - mu * a;
    }
    __syncthreads();
    int gid = blockIdx.x * 256 + tid;   // n*64+f
    int f = tid & 63, n = gid >> 6;
    float sc = lscale[f], sh = lshift[f];
    size_t base = (size_t)n * (R_RUNS * HID) + f;
    float s = 0.f;
    #pragma unroll
    for (int r = 0; r < R_RUNS; ++r) {
        float v = (float)t[base + r * HID];
        v = fmaxf(v * sc + sh, 0.f);
        hOut[base + r * HID] = (bf16)v;
        s += v;
    }
    atomicAdd(&pooled[batch[n] * HID + f], s * (1.0f / R_RUNS));
}

// final: out[g,:] = log_softmax( sum_l pooled5[l][g] @ fcw_l + fcb_l )
__global__ void fc_softmax_kernel(const float* __restrict__ pooled5,
                                  const bf16* __restrict__ params,
                                  const int* __restrict__ cnts, void* __restrict__ out) {
    int g = threadIdx.x;   // 128 threads
    if (g >= NG) return;
    float o[NC];
    #pragma unroll
    for (int c = 0; c < NC; ++c) o[c] = 0.f;
    for (int l = 0; l < NL + 1; ++l) {
        const float* pg = pooled5 + ((size_t)l * NG + g) * HID;
        const bf16* fw = params + PFW + l * (HID * NC);
        for (int k = 0; k < HID; ++k) {
            float p = pg[k];
            #pragma unroll
            for (int c = 0; c < NC; ++c) o[c] += p * (float)fw[k * NC + c];
        }
        #pragma unroll
        for (int c = 0; c < NC; ++c) o[c] += (float)params[PFB + l * NC + c];
    }
    float m = -1e30f;
    #pragma unroll
    for (int c = 0; c < NC; ++c) m = fmaxf(m, o[c]);
    float s = 0.f;
    #pragma unroll
    for (int c = 0; c < NC; ++c) s += expf(o[c] - m);
    float lg = logf(s);
    int f = cnts[0] > 64;
    #pragma unroll
    for (int c = 0; c < NC; ++c) {
        float val = o[c] - m - lg;
        if (f) ((float*)out)[g * NC + c] = val;
        else   ((bf16*)out)[g * NC + c] = (bf16)val;
    }
}

extern "C" void kernel_launch(void* const* d_in, const int* in_sizes, int n_in,
                              void* d_out, int out_size, void* d_ws, size_t ws_size,
                              hipStream_t stream) {
    const void* x     = d_in[0];
    const int*  ei    = (const int*)d_in[1];
    const int*  batch = (const int*)d_in[2];
    const void* maskp = d_in[3];

    char* ws = (char*)d_ws;
    int*   cnts    = (int*)(ws + OFF_FLAGS);
    int*   cursor  = (int*)(ws + OFF_CURSOR);
    float* statsb  = (float*)(ws + OFF_STATS);
    float* pooled5 = (float*)(ws + OFF_POOLED5);
    int*   rowst   = (int*)(ws + OFF_ROWST);
    int*   colbuf  = (int*)(ws + OFF_COL);
    bf16*  params  = (bf16*)(ws + OFF_PARAMS);
    bf16*  xb      = (bf16*)(ws + OFF_XB);
    bf16*  h       = (bf16*)(ws + OFF_H);
    bf16*  z       = (bf16*)(ws + OFF_Z);

    hipMemsetAsync(ws, 0, ZERO_BYTES, stream);   // flags+cursor+stats+pooled5

    detect_kernel<<<64, 256, 0, stream>>>((const unsigned short*)x,
                                          (const unsigned int*)maskp, cnts);
    convert_kernel<<<(CVT_TOT + 255) / 256, 256, 0, stream>>>(
        cnts, x, d_in[4], d_in[5], d_in[6], d_in[7], d_in[8], d_in[9], d_in[10],
        d_in[11], d_in[12], d_in[13], xb, params);

    csr_count_kernel<<<(N_EDGES + 255) / 256, 256, 0, stream>>>(ei, cursor);
    csr_scan_kernel<<<1, 1024, 0, stream>>>(cursor, rowst);
    csr_fill_kernel<<<(N_EDGES + 255) / 256, 256, 0, stream>>>(ei, cursor, colbuf);

    build_h0_kernel<<<(MROWS * 8) / 256, 256, 0, stream>>>(xb, maskp, cnts, h);
    pool0_kernel<<<(N_NODES * HID) / 256, 256, 0, stream>>>(h, batch, pooled5);

    for (int i = 0; i < NL; ++i) {
        float* st1 = statsb + (size_t)(2 * i) * (NCOPY * 128);
        float* st2 = statsb + (size_t)(2 * i + 1) * (NCOPY * 128);

        ag1_kernel<<<N_NODES / 16, 256, 0, stream>>>(
            (const uint32*)h, rowst, colbuf,
            params + PW1 + i * 4096, params + PB1 + i * 64, z, st1);

        gemm64_kernel<<<MROWS / 64, 256, 0, stream>>>(
            z, params + PW2 + i * 4096, params + PB2 + i * 64, z,
            st1, params + PG1 + i * 64, params + PBB1 + i * 64, st2);

        pool_bn_kernel<<<(N_NODES * HID) / 256, 256, 0, stream>>>(
            z, st2, params + PG2 + i * 64, params + PBB2 + i * 64, h, batch,
            pooled5 + (size_t)(i + 1) * NG * HID);
    }

    fc_softmax_kernel<<<1, 128, 0, stream>>>(pooled5, params, cnts, d_out);
}

// Round 12
// 769.262 us; speedup vs baseline: 2.2538x; 1.0659x over previous
//
#include <hip/hip_runtime.h>

#define N_NODES 20000
#define N_EDGES 320000
#define R_RUNS 10
#define HID 64
#define NG 128
#define NC 10
#define NL 4
#define MROWS (R_RUNS * N_NODES)   // 200000
#define BN_EPS 1e-5f
#define NCOPY 16                   // stats copies per buffer
#define TS 72                      // LDS z-tile row stride (bf16 elems)
#define AG_NPB 8                   // ag1 nodes per block (R12: was 16)
#define G2_TILES 5                 // gemm64 64-row tiles per block
#define PB_NPB 16                  // pool_bn nodes per block

typedef __bf16 bf16;
typedef __attribute__((ext_vector_type(8))) __bf16 bf16x8;
typedef __attribute__((ext_vector_type(4))) float f32x4;
typedef unsigned int uint32;

// ---------------- workspace layout (bytes)
constexpr size_t OFF_FLAGS   = 0;          // int[4] counters, pad 256
constexpr size_t OFF_CURSOR  = 256;        // int[20001] -> pad 80384
constexpr size_t OFF_STATS   = 80640;      // f32[8 bufs][16 copies][128] = 65536
constexpr size_t OFF_POOLED5 = 146176;     // f32[5][128][64] = 163840
constexpr size_t ZERO_BYTES  = 310016;
constexpr size_t OFF_ROWST   = 310016;     // int[20001] -> pad 390400
constexpr size_t OFF_COL     = 390400;     // int[320000] -> 1670400
constexpr size_t OFF_PARAMS  = 1670400;    // bf16[37554] -> pad 1745664
constexpr size_t OFF_XB      = 1745664;    // bf16[1280000] -> 4305664
constexpr size_t OFF_H       = 4305664;    // 25,600,000
constexpr size_t OFF_Z       = 29905664;   // 25,600,000 -> end 55,505,664

// params block element offsets (w1/w2 stored PRE-SWIZZLED in B-fragment order)
#define PW1  0
#define PB1  16384
#define PG1  16640
#define PBB1 16896
#define PW2  17152
#define PB2  33536
#define PG2  33792
#define PBB2 34048
#define PFW  34304
#define PFB  37504
#define PTOT 37554
#define CVT_TOT (1280000 + PTOT)

// ---------------- runtime dtype detection (validated R4-R11) ----------------
__global__ void detect_kernel(const unsigned short* __restrict__ xu,
                              const unsigned int* __restrict__ mw,
                              int* __restrict__ cnts) {
    int tid = blockIdx.x * 256 + threadIdx.x;   // 16384 threads
    int insane = 0, lowp = 0, f32w = 0, gt1 = 0;
    for (int i = tid; i < 4096; i += 16384) {
        unsigned int u = xu[2 * i];
        if (((u >> 7) & 0xFFu) >= 0x90u) insane++;
    }
    for (int i = tid; i < 50000; i += 16384) {
        unsigned int w = mw[i];
        if ((w & 0xFFFFu) == 0x3F80u) lowp = 1;
        else if (w == 0x3F800000u) f32w = 1;
        else if (w > 1u) gt1 = 1;
    }
    if (insane) atomicAdd(&cnts[0], insane);
    if (lowp)   atomicOr(&cnts[1], 1);
    if (f32w)   atomicOr(&cnts[2], 1);
    if (gt1)    atomicOr(&cnts[3], 1);
}

__device__ inline bf16 ld_any(const void* p, int i, int f32mode) {
    if (f32mode) return (bf16)((const float*)p)[i];
    return ((const bf16*)p)[i];
}

// convert all float inputs to canonical bf16; w1/w2 written in per-lane
// B-fragment order:
//   Wf[((nt*2+c)*64 + lane)*8 + j] = W[(c*32+(lane>>4)*8+j)*64 + nt*16+(lane&15)]
__global__ void convert_kernel(const int* __restrict__ cnts,
                               const void* x, const void* w1, const void* b1,
                               const void* g1, const void* bb1, const void* w2,
                               const void* b2, const void* g2, const void* bb2,
                               const void* fw, const void* fb,
                               bf16* __restrict__ xb, bf16* __restrict__ params) {
    int t = blockIdx.x * 256 + threadIdx.x;
    if (t >= CVT_TOT) return;
    int f = cnts[0] > 64;
    if (t < 1280000) { xb[t] = ld_any(x, t, f); return; }
    int u = t - 1280000;
    if (u < PB1 || (u >= PW2 && u < PB2)) {       // swizzled weight regions
        const void* src = (u < PB1) ? w1 : w2;
        int v = (u < PB1) ? u : u - PW2;
        int layer = v >> 12, rem = v & 4095;
        int j = rem & 7, lane = (rem >> 3) & 63, ntc = rem >> 9;
        int nt = ntc >> 1, c = ntc & 1;
        int k = c * 32 + (lane >> 4) * 8 + j;
        int n = nt * 16 + (lane & 15);
        params[u] = ld_any(src, layer * 4096 + k * 64 + n, f);
        return;
    }
    const void* src; int base;
    if      (u < PG1)  { src = b1;  base = PB1; }
    else if (u < PBB1) { src = g1;  base = PG1; }
    else if (u < PW2)  { src = bb1; base = PBB1; }
    else if (u < PG2)  { src = b2;  base = PB2; }
    else if (u < PBB2) { src = g2;  base = PG2; }
    else if (u < PFW)  { src = bb2; base = PBB2; }
    else if (u < PFB)  { src = fw;  base = PFW; }
    else               { src = fb;  base = PFB; }
    params[u] = ld_any(src, u - base, f);
}

// h0[(n*10+r)*64+f] = drop[r][n] ? 0 : x[n,f]  (contiguous writes, R7-proven)
__global__ void build_h0_kernel(const bf16* __restrict__ xb, const void* __restrict__ maskp,
                                const int* __restrict__ cnts, bf16* __restrict__ h) {
    int i = blockIdx.x * 256 + threadIdx.x;   // (n*10+r)*8 + c ; 1.6M total
    int c = i & 7;
    int rowid = i >> 3;
    int r = rowid % R_RUNS;
    int n = rowid / R_RUNS;
    size_t midx = (size_t)r * N_NODES + n;
    int w = cnts[1] ? 2 : (cnts[2] ? 4 : (cnts[3] ? 1 : 4));
    int dropped;
    if (w == 1)      dropped = ((const unsigned char*)maskp)[midx] != 0;
    else if (w == 2) dropped = ((const unsigned short*)maskp)[midx] != 0;
    else             dropped = ((const unsigned int*)maskp)[midx] != 0;
    bf16x8 v;
    if (dropped) {
        #pragma unroll
        for (int j = 0; j < 8; ++j) v[j] = (bf16)0.0f;
    } else {
        v = *(const bf16x8*)(xb + (size_t)n * HID + c * 8);
    }
    *(bf16x8*)(h + (size_t)rowid * HID + c * 8) = v;
}

// level-0 raw pool of h0 (R7-proven)
__global__ __launch_bounds__(256) void pool0_kernel(const bf16* __restrict__ t,
                                                    const int* __restrict__ batch,
                                                    float* __restrict__ pooled) {
    int gid = blockIdx.x * 256 + threadIdx.x;   // n*64+f
    int f = gid & 63, n = gid >> 6;
    size_t base = (size_t)n * (R_RUNS * HID) + f;
    float s = 0.f;
    #pragma unroll
    for (int r = 0; r < R_RUNS; ++r) s += (float)t[base + r * HID];
    atomicAdd(&pooled[batch[n] * HID + f], s * (1.0f / R_RUNS));
}

// ---------------- CSR build (keyed by dst) ----------------
__global__ void csr_count_kernel(const int* __restrict__ ei, int* __restrict__ deg) {
    int e = blockIdx.x * 256 + threadIdx.x;
    if (e < N_EDGES) atomicAdd(&deg[ei[N_EDGES + e]], 1);
}

__global__ void csr_scan_kernel(int* __restrict__ deg, int* __restrict__ row_start) {
    __shared__ int lds[1024];
    int tid = threadIdx.x;
    const int CH = 20;
    int base = tid * CH;
    int local[CH];
    int s = 0;
    #pragma unroll
    for (int j = 0; j < CH; ++j) {
        int n = base + j;
        int d = (n < N_NODES) ? deg[n] : 0;
        local[j] = d; s += d;
    }
    lds[tid] = s; __syncthreads();
    for (int off = 1; off < 1024; off <<= 1) {
        int add = (tid >= off) ? lds[tid - off] : 0;
        __syncthreads();
        lds[tid] += add;
        __syncthreads();
    }
    int excl = lds[tid] - s;
    #pragma unroll
    for (int j = 0; j < CH; ++j) {
        int n = base + j;
        if (n < N_NODES) { row_start[n] = excl; deg[n] = excl; excl += local[j]; }
    }
    if (tid == 1023) row_start[N_NODES] = lds[1023];
}

__global__ void csr_fill_kernel(const int* __restrict__ ei, int* __restrict__ cursor,
                                int* __restrict__ col) {
    int e = blockIdx.x * 256 + threadIdx.x;
    if (e < N_EDGES) {
        int src = ei[e];
        int dst = ei[N_EDGES + e];
        int pos = atomicAdd(&cursor[dst], 1);
        col[pos] = src;
    }
}

// ---------------- fused agg + gemm1: block = 8 nodes (80 rows), grid 2500.
// R12: halved block size vs R11 (16) to double blocks/CU and cut barrier
// straggling — ag1 was at 30% occupancy / 2.2 TB/s vs split-agg's 62% / 3.6.
__global__ __launch_bounds__(256) void ag1_kernel(const uint32* __restrict__ hD,
                                                  const int* __restrict__ row_start,
                                                  const int* __restrict__ col,
                                                  const bf16* __restrict__ Wf,
                                                  const bf16* __restrict__ bias,
                                                  bf16* __restrict__ out,
                                                  float* __restrict__ statsOut) {
    __shared__ __align__(16) bf16 zT[AG_NPB * R_RUNS * TS];   // 80 x 72 = 11520 B
    __shared__ float lsum[64], lsq[64];
    uint32* zTu = (uint32*)zT;                                // row stride 36 dwords
    int tid = threadIdx.x;
    int wave = tid >> 6, lane = tid & 63, l16 = lane & 15, quad = lane >> 4;
    int b = blockIdx.x;
    const int NODE_DW = R_RUNS * HID / 2;   // 320

    if (tid < 64) { lsum[tid] = 0.f; lsq[tid] = 0.f; }

    // ---- phase 1: aggregate 2 nodes per wave into LDS
    for (int i = 0; i < AG_NPB / 4; ++i) {
        int nl = wave + 4 * i;              // local node 0..7
        int n = b * AG_NPB + nl;
        size_t base4 = (size_t)n * NODE_DW + lane * 4;
        size_t baset = (size_t)n * NODE_DW + 256 + lane;
        float acc[10];
        {
            uint4 u = *(const uint4*)(hD + base4);
            uint32 tw = hD[baset];
            acc[0] = __uint_as_float(u.x << 16); acc[1] = __uint_as_float(u.x & 0xFFFF0000u);
            acc[2] = __uint_as_float(u.y << 16); acc[3] = __uint_as_float(u.y & 0xFFFF0000u);
            acc[4] = __uint_as_float(u.z << 16); acc[5] = __uint_as_float(u.z & 0xFFFF0000u);
            acc[6] = __uint_as_float(u.w << 16); acc[7] = __uint_as_float(u.w & 0xFFFF0000u);
            acc[8] = __uint_as_float(tw << 16);  acc[9] = __uint_as_float(tw & 0xFFFF0000u);
        }
        int beg = row_start[n], end = row_start[n + 1];
        int idx = beg;
        for (; idx + 4 <= end; idx += 4) {
            uint4 a[4]; uint32 tw[4];
            #pragma unroll
            for (int u = 0; u < 4; ++u) {
                size_t o = (size_t)col[idx + u] * NODE_DW;
                a[u] = *(const uint4*)(hD + o + lane * 4);
                tw[u] = hD[o + 256 + lane];
            }
            #pragma unroll
            for (int u = 0; u < 4; ++u) {
                uint32 wd[4] = {a[u].x, a[u].y, a[u].z, a[u].w};
                #pragma unroll
                for (int c = 0; c < 4; ++c) {
                    acc[2 * c]     += __uint_as_float(wd[c] << 16);
                    acc[2 * c + 1] += __uint_as_float(wd[c] & 0xFFFF0000u);
                }
                acc[8] += __uint_as_float(tw[u] << 16);
                acc[9] += __uint_as_float(tw[u] & 0xFFFF0000u);
            }
        }
        for (; idx < end; ++idx) {
            size_t o = (size_t)col[idx] * NODE_DW;
            uint4 a0 = *(const uint4*)(hD + o + lane * 4);
            uint32 t0 = hD[o + 256 + lane];
            uint32 wd[4] = {a0.x, a0.y, a0.z, a0.w};
            #pragma unroll
            for (int c = 0; c < 4; ++c) {
                acc[2 * c]     += __uint_as_float(wd[c] << 16);
                acc[2 * c + 1] += __uint_as_float(wd[c] & 0xFFFF0000u);
            }
            acc[8] += __uint_as_float(t0 << 16);
            acc[9] += __uint_as_float(t0 & 0xFFFF0000u);
        }
        #pragma unroll
        for (int c = 0; c < 5; ++c) {
            int d = (c < 4) ? (lane * 4 + c) : (256 + lane);
            int rL = nl * R_RUNS + (d >> 5);
            int fp = d & 31;
            unsigned short lo = __builtin_bit_cast(unsigned short, (bf16)acc[2 * c]);
            unsigned short hi = __builtin_bit_cast(unsigned short, (bf16)acc[2 * c + 1]);
            zTu[rL * (TS / 2) + fp] = (uint32)lo | ((uint32)hi << 16);
        }
    }
    __syncthreads();

    // ---- phase 2: gemm1 from LDS, 5 row-groups of 16 over 4 waves
    bf16x8 bfr[4][2];
    #pragma unroll
    for (int nt = 0; nt < 4; ++nt)
        #pragma unroll
        for (int c = 0; c < 2; ++c)
            bfr[nt][c] = *(const bf16x8*)(Wf + (size_t)((nt * 2 + c) * 64 + lane) * 8);
    float bvs[4];
    #pragma unroll
    for (int nt = 0; nt < 4; ++nt) bvs[nt] = (float)bias[nt * 16 + l16];

    for (int g = wave; g < 5; g += 4) {
        const bf16* tp = &zT[(g * 16 + l16) * TS];
        bf16x8 a0 = *(const bf16x8*)(tp + quad * 8);
        bf16x8 a1 = *(const bf16x8*)(tp + 32 + quad * 8);
        f32x4 acc[4];
        #pragma unroll
        for (int nt = 0; nt < 4; ++nt) acc[nt] = (f32x4){bvs[nt], bvs[nt], bvs[nt], bvs[nt]};
        #pragma unroll
        for (int nt = 0; nt < 4; ++nt) {
            acc[nt] = __builtin_amdgcn_mfma_f32_16x16x32_bf16(a0, bfr[nt][0], acc[nt], 0, 0, 0);
            acc[nt] = __builtin_amdgcn_mfma_f32_16x16x32_bf16(a1, bfr[nt][1], acc[nt], 0, 0, 0);
        }
        size_t rowBase = (size_t)b * (AG_NPB * R_RUNS) + g * 16;
        #pragma unroll
        for (int nt = 0; nt < 4; ++nt) {
            float ss = 0.f, qq = 0.f;
            #pragma unroll
            for (int reg = 0; reg < 4; ++reg) {
                float v = acc[nt][reg];
                ss += v; qq += v * v;
                out[(rowBase + quad * 4 + reg) * HID + nt * 16 + l16] = (bf16)v;
            }
            atomicAdd(&lsum[nt * 16 + l16], ss);
            atomicAdd(&lsq[nt * 16 + l16], qq);
        }
    }
    __syncthreads();
    if (tid < 64) {
        int copy = b & (NCOPY - 1);
        atomicAdd(&statsOut[copy * 128 + tid], lsum[tid]);
        atomicAdd(&statsOut[copy * 128 + 64 + tid], lsq[tid]);
    }
}

// ---------------- gemm2: 320 rows/block (5 tiles of 64), grid 625.
// R12: amortizes the per-block stats-reduce (8KB) + W-frag load over 5x rows.
// out = bn_relu(in) @ W + bias, + stats2. in/out may alias per-wave-slice.
__global__ __launch_bounds__(256) void gemm64_kernel(const bf16* in,
                                                     const bf16* __restrict__ Wf,
                                                     const bf16* __restrict__ bias,
                                                     bf16* out,
                                                     const float* __restrict__ statsIn,
                                                     const bf16* __restrict__ gammaIn,
                                                     const bf16* __restrict__ betaIn,
                                                     float* __restrict__ statsOut) {
    __shared__ float lstat[128];
    __shared__ float lscale[64], lshift[64];
    __shared__ float lsum[64], lsq[64];
    int tid = threadIdx.x;
    int wave = tid >> 6, lane = tid & 63, l16 = lane & 15, quad = lane >> 4;

    if (tid < 128) {
        float s = 0.f;
        #pragma unroll
        for (int k = 0; k < NCOPY; ++k) s += statsIn[k * 128 + tid];
        lstat[tid] = s;
    }
    if (tid < 64) { lsum[tid] = 0.f; lsq[tid] = 0.f; }
    __syncthreads();
    if (tid < 64) {
        float mu = lstat[tid] * (1.0f / MROWS);
        float var = lstat[tid + 64] * (1.0f / MROWS) - mu * mu;
        float rs = rsqrtf(var + BN_EPS);
        float a = (float)gammaIn[tid] * rs;
        lscale[tid] = a;
        lshift[tid] = (float)betaIn[tid] - mu * a;
    }
    __syncthreads();

    bf16x8 bfrag[4][2];
    #pragma unroll
    for (int nt = 0; nt < 4; ++nt)
        #pragma unroll
        for (int c = 0; c < 2; ++c)
            bfrag[nt][c] = *(const bf16x8*)(Wf + (size_t)((nt * 2 + c) * 64 + lane) * 8);
    float bvs[4];
    #pragma unroll
    for (int nt = 0; nt < 4; ++nt) bvs[nt] = (float)bias[nt * 16 + l16];

    for (int t5 = 0; t5 < G2_TILES; ++t5) {
        size_t rowBase = (size_t)blockIdx.x * (G2_TILES * 64) + t5 * 64 + wave * 16;
        f32x4 acc[4];
        #pragma unroll
        for (int nt = 0; nt < 4; ++nt) acc[nt] = (f32x4){bvs[nt], bvs[nt], bvs[nt], bvs[nt]};

        size_t row = rowBase + l16;
        bf16x8 afrag[2];
        #pragma unroll
        for (int c = 0; c < 2; ++c) {
            int k0 = c * 32 + quad * 8;
            bf16x8 v = *(const bf16x8*)(in + row * HID + k0);
            #pragma unroll
            for (int j = 0; j < 8; ++j) {
                float f = (float)v[j] * lscale[k0 + j] + lshift[k0 + j];
                v[j] = (bf16)fmaxf(f, 0.f);
            }
            afrag[c] = v;
        }

        #pragma unroll
        for (int nt = 0; nt < 4; ++nt) {
            acc[nt] = __builtin_amdgcn_mfma_f32_16x16x32_bf16(afrag[0], bfrag[nt][0], acc[nt], 0, 0, 0);
            acc[nt] = __builtin_amdgcn_mfma_f32_16x16x32_bf16(afrag[1], bfrag[nt][1], acc[nt], 0, 0, 0);
        }

        #pragma unroll
        for (int nt = 0; nt < 4; ++nt) {
            float s = 0.f, q = 0.f;
            #pragma unroll
            for (int reg = 0; reg < 4; ++reg) {
                float v = acc[nt][reg];
                s += v; q += v * v;
                out[(rowBase + quad * 4 + reg) * HID + nt * 16 + l16] = (bf16)v;
            }
            atomicAdd(&lsum[nt * 16 + l16], s);
            atomicAdd(&lsq[nt * 16 + l16], q);
        }
    }
    __syncthreads();
    if (tid < 64) {
        int copy = blockIdx.x & (NCOPY - 1);
        atomicAdd(&statsOut[copy * 128 + tid], lsum[tid]);
        atomicAdd(&statsOut[copy * 128 + 64 + tid], lsq[tid]);
    }
}

// fused stats reduce + BN+ReLU + h-materialize + pool; 16 nodes/block (grid
// 1250, 4 nodes/thread) — stats-reduce paid 1250x not 5000x.
__global__ __launch_bounds__(256) void pool_bn_kernel(const bf16* __restrict__ t,
                                                      const float* __restrict__ statsIn,
                                                      const bf16* __restrict__ gammaIn,
                                                      const bf16* __restrict__ betaIn,
                                                      bf16* __restrict__ hOut,
                                                      const int* __restrict__ batch,
                                                      float* __restrict__ pooled) {
    __shared__ float lstat[128], lscale[64], lshift[64];
    int tid = threadIdx.x;
    if (tid < 128) {
        float s = 0.f;
        #pragma unroll
        for (int k = 0; k < NCOPY; ++k) s += statsIn[k * 128 + tid];
        lstat[tid] = s;
    }
    __syncthreads();
    if (tid < 64) {
        float mu = lstat[tid] * (1.0f / MROWS);
        float var = lstat[tid + 64] * (1.0f / MROWS) - mu * mu;
        float rs = rsqrtf(var + BN_EPS);
        float a = (float)gammaIn[tid] * rs;
        lscale[tid] = a;
        lshift[tid] = (float)betaIn[tid] - mu * a;
    }
    __syncthreads();
    int f = tid & 63, nsub = tid >> 6;
    float sc = lscale[f], sh = lshift[f];
    #pragma unroll
    for (int j = 0; j < PB_NPB / 4; ++j) {
        int n = blockIdx.x * PB_NPB + j * 4 + nsub;
        size_t base = (size_t)n * (R_RUNS * HID) + f;
        float s = 0.f;
        #pragma unroll
        for (int r = 0; r < R_RUNS; ++r) {
            float v = (float)t[base + r * HID];
            v = fmaxf(v * sc + sh, 0.f);
            hOut[base + r * HID] = (bf16)v;
            s += v;
        }
        atomicAdd(&pooled[batch[n] * HID + f], s * (1.0f / R_RUNS));
    }
}

// final: out[g,:] = log_softmax( sum_l pooled5[l][g] @ fcw_l + fcb_l )
__global__ void fc_softmax_kernel(const float* __restrict__ pooled5,
                                  const bf16* __restrict__ params,
                                  const int* __restrict__ cnts, void* __restrict__ out) {
    int g = threadIdx.x;   // 128 threads
    if (g >= NG) return;
    float o[NC];
    #pragma unroll
    for (int c = 0; c < NC; ++c) o[c] = 0.f;
    for (int l = 0; l < NL + 1; ++l) {
        const float* pg = pooled5 + ((size_t)l * NG + g) * HID;
        const bf16* fw = params + PFW + l * (HID * NC);
        for (int k = 0; k < HID; ++k) {
            float p = pg[k];
            #pragma unroll
            for (int c = 0; c < NC; ++c) o[c] += p * (float)fw[k * NC + c];
        }
        #pragma unroll
        for (int c = 0; c < NC; ++c) o[c] += (float)params[PFB + l * NC + c];
    }
    float m = -1e30f;
    #pragma unroll
    for (int c = 0; c < NC; ++c) m = fmaxf(m, o[c]);
    float s = 0.f;
    #pragma unroll
    for (int c = 0; c < NC; ++c) s += expf(o[c] - m);
    float lg = logf(s);
    int f = cnts[0] > 64;
    #pragma unroll
    for (int c = 0; c < NC; ++c) {
        float val = o[c] - m - lg;
        if (f) ((float*)out)[g * NC + c] = val;
        else   ((bf16*)out)[g * NC + c] = (bf16)val;
    }
}

extern "C" void kernel_launch(void* const* d_in, const int* in_sizes, int n_in,
                              void* d_out, int out_size, void* d_ws, size_t ws_size,
                              hipStream_t stream) {
    const void* x     = d_in[0];
    const int*  ei    = (const int*)d_in[1];
    const int*  batch = (const int*)d_in[2];
    const void* maskp = d_in[3];

    char* ws = (char*)d_ws;
    int*   cnts    = (int*)(ws + OFF_FLAGS);
    int*   cursor  = (int*)(ws + OFF_CURSOR);
    float* statsb  = (float*)(ws + OFF_STATS);
    float* pooled5 = (float*)(ws + OFF_POOLED5);
    int*   rowst   = (int*)(ws + OFF_ROWST);
    int*   colbuf  = (int*)(ws + OFF_COL);
    bf16*  params  = (bf16*)(ws + OFF_PARAMS);
    bf16*  xb      = (bf16*)(ws + OFF_XB);
    bf16*  h       = (bf16*)(ws + OFF_H);
    bf16*  z       = (bf16*)(ws + OFF_Z);

    hipMemsetAsync(ws, 0, ZERO_BYTES, stream);   // flags+cursor+stats+pooled5

    detect_kernel<<<64, 256, 0, stream>>>((const unsigned short*)x,
                                          (const unsigned int*)maskp, cnts);
    convert_kernel<<<(CVT_TOT + 255) / 256, 256, 0, stream>>>(
        cnts, x, d_in[4], d_in[5], d_in[6], d_in[7], d_in[8], d_in[9], d_in[10],
        d_in[11], d_in[12], d_in[13], xb, params);

    csr_count_kernel<<<(N_EDGES + 255) / 256, 256, 0, stream>>>(ei, cursor);
    csr_scan_kernel<<<1, 1024, 0, stream>>>(cursor, rowst);
    csr_fill_kernel<<<(N_EDGES + 255) / 256, 256, 0, stream>>>(ei, cursor, colbuf);

    build_h0_kernel<<<(MROWS * 8) / 256, 256, 0, stream>>>(xb, maskp, cnts, h);
    pool0_kernel<<<(N_NODES * HID) / 256, 256, 0, stream>>>(h, batch, pooled5);

    for (int i = 0; i < NL; ++i) {
        float* st1 = statsb + (size_t)(2 * i) * (NCOPY * 128);
        float* st2 = statsb + (size_t)(2 * i + 1) * (NCOPY * 128);

        ag1_kernel<<<N_NODES / AG_NPB, 256, 0, stream>>>(
            (const uint32*)h, rowst, colbuf,
            params + PW1 + i * 4096, params + PB1 + i * 64, z, st1);

        gemm64_kernel<<<MROWS / (G2_TILES * 64), 256, 0, stream>>>(
            z, params + PW2 + i * 4096, params + PB2 + i * 64, z,
            st1, params + PG1 + i * 64, params + PBB1 + i * 64, st2);

        pool_bn_kernel<<<N_NODES / PB_NPB, 256, 0, stream>>>(
            z, st2, params + PG2 + i * 64, params + PBB2 + i * 64, h, batch,
            pooled5 + (size_t)(i + 1) * NG * HID);
    }

    fc_softmax_kernel<<<1, 128, 0, stream>>>(pooled5, params, cnts, d_out);
}